// Round 11
// baseline (1507.329 us; speedup 1.0000x reference)
//
#include <hip/hip_runtime.h>
#include <stdint.h>

#define TT 16384
#define HH 4096

typedef uint8_t u8;
typedef uint32_t u32;
typedef __attribute__((ext_vector_type(16))) float f32x16;
typedef __attribute__((ext_vector_type(8))) int i32x8;

// ---- fp8 e4m3 (OCP) pack: 4 floats -> 4 bytes, RNE, saturating ----
__device__ __forceinline__ u32 cvt4_fp8(float a, float b, float c, float d) {
  u32 v = 0;
  v = __builtin_amdgcn_cvt_pk_fp8_f32(a, b, v, false);  // low word
  v = __builtin_amdgcn_cvt_pk_fp8_f32(c, d, v, true);   // high word
  return v;
}

__device__ __forceinline__ void gl_lds16(const void* g, void* l) {
  __builtin_amdgcn_global_load_lds(
      (const __attribute__((address_space(1))) void*)g,
      (__attribute__((address_space(3))) void*)l, 16, 0, 0);
}

struct A2 { uint4 lo, hi; };
__device__ __forceinline__ A2 ldA32(const u8* p) {
  A2 r;
  r.lo = ((const uint4*)p)[0];
  r.hi = ((const uint4*)p)[1];
  return r;
}
__device__ __forceinline__ i32x8 packA(const A2& a) {
  i32x8 r;
  r[0] = (int)a.lo.x; r[1] = (int)a.lo.y; r[2] = (int)a.lo.z; r[3] = (int)a.lo.w;
  r[4] = (int)a.hi.x; r[5] = (int)a.hi.y; r[6] = (int)a.hi.z; r[7] = (int)a.hi.w;
  return r;
}
__device__ __forceinline__ i32x8 ld32B(const u8* p0, const u8* p1) {
  const uint4 a = *(const uint4*)p0;
  const uint4 b = *(const uint4*)p1;
  i32x8 r;
  r[0] = (int)a.x; r[1] = (int)a.y; r[2] = (int)a.z; r[3] = (int)a.w;
  r[4] = (int)b.x; r[5] = (int)b.y; r[6] = (int)b.z; r[7] = (int)b.w;
  return r;
}

// ---- weight quantize + transpose: w[K][N] fp32 (on fp8 grid) -> wq[N][K] fp8 (plain)
__global__ __launch_bounds__(256) void kwquant(const float* __restrict__ w,
                                               u8* __restrict__ wq) {
  __shared__ __align__(16) u8 tile[64][68];
  const int n0 = blockIdx.x * 64;
  const int k0 = blockIdx.y * 64;
  const int t = threadIdx.x;
  const int tr = t >> 4, tc = t & 15;
#pragma unroll
  for (int p = 0; p < 4; ++p) {
    const int kl = p * 16 + tr;
    const float4 v = *(const float4*)(w + (size_t)(k0 + kl) * HH + n0 + tc * 4);
    const u32 pk = cvt4_fp8(v.x, v.y, v.z, v.w);
    tile[tc * 4 + 0][kl] = (u8)(pk);
    tile[tc * 4 + 1][kl] = (u8)(pk >> 8);
    tile[tc * 4 + 2][kl] = (u8)(pk >> 16);
    tile[tc * 4 + 3][kl] = (u8)(pk >> 24);
  }
  __syncthreads();
  const int jr = t >> 2;
  const int kc = (t & 3) * 16;
  uint4 ov;
  ov.x = *(const u32*)&tile[jr][kc + 0];
  ov.y = *(const u32*)&tile[jr][kc + 4];
  ov.z = *(const u32*)&tile[jr][kc + 8];
  ov.w = *(const u32*)&tile[jr][kc + 12];
  *(uint4*)(wq + (size_t)(n0 + jr) * HH + k0 + kc) = ov;
}

__device__ __forceinline__ float wred_sum(float v) {
#pragma unroll
  for (int o = 32; o; o >>= 1) v += __shfl_down(v, o, 64);
  return v;
}
__device__ __forceinline__ float wred_max(float v) {
#pragma unroll
  for (int o = 32; o; o >>= 1) v = fmaxf(v, __shfl_down(v, o, 64));
  return v;
}

// MODE 0: src=x, write resid=sqrt(x), quantize rmsnorm(x,nw) -> qout,sout
// MODE 1: src=resid, quantize rmsnorm(resid,nw) -> qout,sout
// MODE 2: src=resid, write y=rmsnorm(resid,nw) fp32 -> yout
template <int MODE>
__global__ __launch_bounds__(256) void knorm(const float* __restrict__ src,
                                             const float* __restrict__ nw,
                                             float* __restrict__ resid_out,
                                             u8* __restrict__ qout,
                                             float* __restrict__ sout,
                                             float* __restrict__ yout) {
  __shared__ float red[4];
  __shared__ float redm[4];
  const int row = blockIdx.x;
  const int t = threadIdx.x;
  const int lane = t & 63, wid = t >> 6;
  const float* rp = src + (size_t)row * HH;

  float4 xv[4];
  float ssq = 0.f;
#pragma unroll
  for (int p = 0; p < 4; ++p) {
    xv[p] = *((const float4*)rp + p * 256 + t);
    ssq += xv[p].x * xv[p].x;
    ssq += xv[p].y * xv[p].y;
    ssq += xv[p].z * xv[p].z;
    ssq += xv[p].w * xv[p].w;
  }
  if (MODE == 0) {
    float* rr = resid_out + (size_t)row * HH;
#pragma unroll
    for (int p = 0; p < 4; ++p) {
      float4 r4;
      r4.x = sqrtf(xv[p].x); r4.y = sqrtf(xv[p].y);
      r4.z = sqrtf(xv[p].z); r4.w = sqrtf(xv[p].w);
      *((float4*)rr + p * 256 + t) = r4;
    }
  }
  ssq = wred_sum(ssq);
  if (lane == 0) red[wid] = ssq;
  __syncthreads();
  const float ms = (((red[0] + red[1]) + red[2]) + red[3]) * (1.0f / HH);
  const float inv = 1.0f / sqrtf(ms + 1e-6f);

  float y[16];
  float amax = 0.f;
#pragma unroll
  for (int p = 0; p < 4; ++p) {
    const float4 wv = *((const float4*)nw + p * 256 + t);
    y[p * 4 + 0] = (xv[p].x * inv) * wv.x;
    y[p * 4 + 1] = (xv[p].y * inv) * wv.y;
    y[p * 4 + 2] = (xv[p].z * inv) * wv.z;
    y[p * 4 + 3] = (xv[p].w * inv) * wv.w;
    amax = fmaxf(amax, fabsf(y[p * 4 + 0]));
    amax = fmaxf(amax, fabsf(y[p * 4 + 1]));
    amax = fmaxf(amax, fabsf(y[p * 4 + 2]));
    amax = fmaxf(amax, fabsf(y[p * 4 + 3]));
  }

  if (MODE == 2) {
    float* yp = yout + (size_t)row * HH;
#pragma unroll
    for (int p = 0; p < 4; ++p) {
      float4 o;
      o.x = y[p * 4 + 0]; o.y = y[p * 4 + 1];
      o.z = y[p * 4 + 2]; o.w = y[p * 4 + 3];
      *((float4*)yp + p * 256 + t) = o;
    }
    return;
  }

  amax = wred_max(amax);
  if (lane == 0) redm[wid] = amax;
  __syncthreads();
  const float bmax = fmaxf(fmaxf(redm[0], redm[1]), fmaxf(redm[2], redm[3]));
  const float sval = fmaxf(bmax / 448.0f, 1e-10f);  // ref: max|y|/448, floor 1e-10

  u32* qp = (u32*)(qout + (size_t)row * HH);
#pragma unroll
  for (int p = 0; p < 4; ++p) {
    float q0 = fminf(fmaxf(y[p * 4 + 0] / sval, -448.f), 448.f);
    float q1 = fminf(fmaxf(y[p * 4 + 1] / sval, -448.f), 448.f);
    float q2 = fminf(fmaxf(y[p * 4 + 2] / sval, -448.f), 448.f);
    float q3 = fminf(fmaxf(y[p * 4 + 3] / sval, -448.f), 448.f);
    qp[p * 256 + t] = cvt4_fp8(q0, q1, q2, q3);
  }
  if (t == 0) sout[row] = sval;
}

// ---- fp8 GEMM via MX-scaled MFMA (unit scales => exact fp8 matmul at 2x rate)
// C[t,j] = sum_k Aq[t,k]*Bq[j,k]; resid[t,j] += C*s[t]*wsc[j]
// Round-11 change: A is wave-private -> load A global->VGPR directly (no LDS),
// double-buffered across an unroll-2 loop (static register sets a0/a1).
// Only B goes through LDS: 3-buffer ring (24 KiB total), prefetch-2.
// LDS demand per block-iter halves (reads 32->16 b128, writes 16->8 KB).
// Explicit counted vmcnt covers the B gl_lds ring only (compiler auto-waits
// the A-register dependency). Issue slots per iter j: [A(j+1) 4][B(j+2) 2].
// Ops younger than B(j) at iter-j wait = A(j)4+B(j+1)2+A(j+1)4+B(j+2)2 = 12
// steady; tail: j=NT-2 -> 10, j=NT-1 -> 4.
// Grouped XCD swizzle (R10, verified FETCH -30%): 4x4 tile groups = 4 MB
// working set resident in the per-XCD L2.
// Frag layout (32x32x64 f8f6f4): lane l -> row/col = l&31, k = (l>>5)*32+byte.
// C/D: col=lane&31, row=(reg&3)+8*(reg>>2)+4*(lane>>5)  [HW-verified m74/m101].
__global__ __launch_bounds__(256) void kgemm(const u8* __restrict__ Aq,
                                             const u8* __restrict__ Bq,
                                             const float* __restrict__ srow,
                                             const float* __restrict__ wsc,
                                             float* __restrict__ resid) {
  constexpr int K = HH, N = HH;
  constexpr int NT = K / 64;  // 64 (even)
  __shared__ __align__(16) u8 smB[3 * 128 * 64];  // 24 KiB, B-only ring

  // grouped 2-level swizzle (R10): 4x4 (tm,tn) groups per XCD -> 4 MB L2 set
  const int bidraw = blockIdx.x;
  const int xcd = bidraw & 7;
  const int c = bidraw >> 3;            // 0..511
  const int g = c >> 4;                 // 32 groups of 16 blocks
  const int gr = g >> 3, gc = g & 7;    // 4 x 8 grid of groups
  const int gm = (c >> 2) & 3, gn = c & 3;
  const int tm = xcd * 16 + gr * 4 + gm;  // 0..127
  const int tn = gc * 4 + gn;             // 0..31
  const int row0 = tm * 128, col0 = tn * 128;

  const int t = threadIdx.x;
  const int lane = t & 63, wid = t >> 6;
  const int wr = wid >> 1, wc = wid & 1;
  const int rl32 = lane & 31, hi = lane >> 5;

  f32x16 acc[2][2];
#pragma unroll
  for (int m = 0; m < 2; ++m)
#pragma unroll
    for (int n = 0; n < 2; ++n) acc[m][n] = (f32x16)0.f;

  // A direct-load row pointers (plain layout, no swizzle): lane reads bytes
  // [k0 + hi*32, +32) of row row0 + wr*64 + m*32 + rl32.
  const u8* apA[2];
#pragma unroll
  for (int m = 0; m < 2; ++m)
    apA[m] = Aq + (size_t)(row0 + wr * 64 + m * 32 + rl32) * K + hi * 32;

  // B staging addresses (16B-block swizzle cb ^= (r>>1)&3, inverse on source)
  int boffg[2], ldso[2];
#pragma unroll
  for (int p = 0; p < 2; ++p) {
    const int off = (wid * 2 + p) * 1024 + lane * 16;
    const int r = off >> 6;
    const int cb = ((off >> 4) & 3) ^ ((r >> 1) & 3);
    boffg[p] = (col0 + r) * K + cb * 16;
    ldso[p] = off;
  }

  // B fragment read offsets within a buffer
  int bro[2][2];
#pragma unroll
  for (int n = 0; n < 2; ++n) {
    const int r = wc * 64 + n * 32 + rl32;
    const int swz = (r >> 1) & 3;
    bro[n][0] = r * 64 + ((hi * 2) ^ swz) * 16;
    bro[n][1] = r * 64 + ((hi * 2 + 1) ^ swz) * 16;
  }

  // prologue: stage B(0)->buf0, B(1)->buf1; load A(0) into set a0
#pragma unroll
  for (int p = 0; p < 2; ++p) gl_lds16(Bq + boffg[p], smB + ldso[p]);
#pragma unroll
  for (int p = 0; p < 2; ++p) gl_lds16(Bq + boffg[p] + 64, smB + 8192 + ldso[p]);
  A2 a0[2], a1[2];
#pragma unroll
  for (int m = 0; m < 2; ++m) a0[m] = ldA32(apA[m]);

  int bc = 0;  // compute buffer for even iter of the pair
  for (int it = 0; it < NT; it += 2) {
    const int b_even = bc;
    const int b_odd = (bc == 2) ? 0 : bc + 1;
    const int b_st0 = (b_odd == 2) ? 0 : b_odd + 1;  // stage target B(it+2)
    const int b_st1 = b_even;                        // stage target B(it+3)

    // ---- even iteration: compute tile it with a0 ----
    if (it + 1 < NT) {
#pragma unroll
      for (int m = 0; m < 2; ++m) a1[m] = ldA32(apA[m] + (it + 1) * 64);
    }
    if (it + 2 < NT) {
      const size_t ko = (size_t)(it + 2) * 64;
#pragma unroll
      for (int p = 0; p < 2; ++p)
        gl_lds16(Bq + boffg[p] + ko, smB + b_st0 * 8192 + ldso[p]);
      asm volatile("s_waitcnt vmcnt(12)" ::: "memory");  // B(it) landed
    } else {
      asm volatile("s_waitcnt vmcnt(10)" ::: "memory");  // tail (it=NT-2)
    }
    __builtin_amdgcn_s_barrier();
    __builtin_amdgcn_sched_barrier(0);
    {
      const u8* sB = smB + b_even * 8192;
      const i32x8 bv0 = ld32B(sB + bro[0][0], sB + bro[0][1]);
      const i32x8 bv1 = ld32B(sB + bro[1][0], sB + bro[1][1]);
      __builtin_amdgcn_s_setprio(1);
#pragma unroll
      for (int m = 0; m < 2; ++m) {
        const i32x8 av = packA(a0[m]);
        acc[m][0] = __builtin_amdgcn_mfma_scale_f32_32x32x64_f8f6f4(
            av, bv0, acc[m][0], 0, 0, 0, 0x7f7f7f7f, 0, 0x7f7f7f7f);
        acc[m][1] = __builtin_amdgcn_mfma_scale_f32_32x32x64_f8f6f4(
            av, bv1, acc[m][1], 0, 0, 0, 0x7f7f7f7f, 0, 0x7f7f7f7f);
      }
      __builtin_amdgcn_s_setprio(0);
    }
    __builtin_amdgcn_sched_barrier(0);
    __builtin_amdgcn_s_barrier();

    // ---- odd iteration: compute tile it+1 with a1 ----
    if (it + 2 < NT) {
#pragma unroll
      for (int m = 0; m < 2; ++m) a0[m] = ldA32(apA[m] + (it + 2) * 64);
    }
    if (it + 3 < NT) {
      const size_t ko = (size_t)(it + 3) * 64;
#pragma unroll
      for (int p = 0; p < 2; ++p)
        gl_lds16(Bq + boffg[p] + ko, smB + b_st1 * 8192 + ldso[p]);
      asm volatile("s_waitcnt vmcnt(12)" ::: "memory");  // B(it+1) landed
    } else {
      asm volatile("s_waitcnt vmcnt(4)" ::: "memory");   // tail (it+1=NT-1)
    }
    __builtin_amdgcn_s_barrier();
    __builtin_amdgcn_sched_barrier(0);
    {
      const u8* sB = smB + b_odd * 8192;
      const i32x8 bv0 = ld32B(sB + bro[0][0], sB + bro[0][1]);
      const i32x8 bv1 = ld32B(sB + bro[1][0], sB + bro[1][1]);
      __builtin_amdgcn_s_setprio(1);
#pragma unroll
      for (int m = 0; m < 2; ++m) {
        const i32x8 av = packA(a1[m]);
        acc[m][0] = __builtin_amdgcn_mfma_scale_f32_32x32x64_f8f6f4(
            av, bv0, acc[m][0], 0, 0, 0, 0x7f7f7f7f, 0, 0x7f7f7f7f);
        acc[m][1] = __builtin_amdgcn_mfma_scale_f32_32x32x64_f8f6f4(
            av, bv1, acc[m][1], 0, 0, 0, 0x7f7f7f7f, 0, 0x7f7f7f7f);
      }
      __builtin_amdgcn_s_setprio(0);
    }
    __builtin_amdgcn_sched_barrier(0);
    __builtin_amdgcn_s_barrier();

    bc = (bc + 2 > 2) ? bc - 1 : bc + 2;  // (bc + 2) % 3
  }

  // epilogue: resid += (acc * s_token) * wscale_col
  const int cc = rl32;
  const int rb = hi * 4;
  float wvv[2];
#pragma unroll
  for (int n = 0; n < 2; ++n) wvv[n] = wsc[col0 + wc * 64 + n * 32 + cc];
#pragma unroll
  for (int m = 0; m < 2; ++m) {
#pragma unroll
    for (int g2 = 0; g2 < 4; ++g2) {
#pragma unroll
      for (int j = 0; j < 4; ++j) {
        const int row = row0 + wr * 64 + m * 32 + g2 * 8 + rb + j;
        const float sv = srow[row];
#pragma unroll
        for (int n = 0; n < 2; ++n) {
          const int col = col0 + wc * 64 + n * 32 + cc;
          const size_t idx = (size_t)row * N + col;
          resid[idx] = resid[idx] + (acc[m][n][g2 * 4 + j] * sv) * wvv[n];
        }
      }
    }
  }
}

extern "C" void kernel_launch(void* const* d_in, const int* in_sizes, int n_in,
                              void* d_out, int out_size, void* d_ws, size_t ws_size,
                              hipStream_t stream) {
  const float* x   = (const float*)d_in[0];
  const float* nw0 = (const float*)d_in[1];
  const float* nw1 = (const float*)d_in[2];
  const float* nw2 = (const float*)d_in[3];
  const float* w0  = (const float*)d_in[4];
  const float* w1  = (const float*)d_in[5];
  const float* ws0 = (const float*)d_in[6];
  const float* ws1 = (const float*)d_in[7];
  float* out = (float*)d_out;

  // workspace: q (T*H fp8) | w0q (H*H fp8) | w1q (H*H fp8) | s (T fp32)  ~= 96.1 MiB
  u8* q = (u8*)d_ws;
  u8* w0q = q + (size_t)TT * HH;
  u8* w1q = w0q + (size_t)HH * HH;
  float* sbuf = (float*)(w1q + (size_t)HH * HH);

  dim3 wg(HH / 64, HH / 64);
  kwquant<<<wg, 256, 0, stream>>>(w0, w0q);
  kwquant<<<wg, 256, 0, stream>>>(w1, w1q);

  knorm<0><<<TT, 256, 0, stream>>>(x, nw0, out, q, sbuf, nullptr);
  kgemm<<<(TT / 128) * (HH / 128), 256, 0, stream>>>(q, w0q, sbuf, ws0, out);
  knorm<1><<<TT, 256, 0, stream>>>(out, nw1, nullptr, q, sbuf, nullptr);
  kgemm<<<(TT / 128) * (HH / 128), 256, 0, stream>>>(q, w1q, sbuf, ws1, out);
  knorm<2><<<TT, 256, 0, stream>>>(out, nw2, nullptr, nullptr, nullptr, out);
}

// Round 14
// 1215.642 us; speedup vs baseline: 1.2399x; 1.2399x over previous
//
#include <hip/hip_runtime.h>
#include <stdint.h>

#define TT 16384
#define HH 4096

typedef uint8_t u8;
typedef uint32_t u32;
typedef __attribute__((ext_vector_type(16))) float f32x16;
typedef __attribute__((ext_vector_type(8))) int i32x8;

// ---- fp8 e4m3 (OCP) pack: 4 floats -> 4 bytes, RNE, saturating ----
__device__ __forceinline__ u32 cvt4_fp8(float a, float b, float c, float d) {
  u32 v = 0;
  v = __builtin_amdgcn_cvt_pk_fp8_f32(a, b, v, false);  // low word
  v = __builtin_amdgcn_cvt_pk_fp8_f32(c, d, v, true);   // high word
  return v;
}

__device__ __forceinline__ void gl_lds16(const void* g, void* l) {
  __builtin_amdgcn_global_load_lds(
      (const __attribute__((address_space(1))) void*)g,
      (__attribute__((address_space(3))) void*)l, 16, 0, 0);
}

__device__ __forceinline__ i32x8 ld32B(const u8* p0, const u8* p1) {
  const uint4 a = *(const uint4*)p0;
  const uint4 b = *(const uint4*)p1;
  i32x8 r;
  r[0] = (int)a.x; r[1] = (int)a.y; r[2] = (int)a.z; r[3] = (int)a.w;
  r[4] = (int)b.x; r[5] = (int)b.y; r[6] = (int)b.z; r[7] = (int)b.w;
  return r;
}

// ---- weight quantize + transpose: w[K][N] fp32 (on fp8 grid) -> wq[N][K] fp8 (plain)
__global__ __launch_bounds__(256) void kwquant(const float* __restrict__ w,
                                               u8* __restrict__ wq) {
  __shared__ __align__(16) u8 tile[64][68];
  const int n0 = blockIdx.x * 64;
  const int k0 = blockIdx.y * 64;
  const int t = threadIdx.x;
  const int tr = t >> 4, tc = t & 15;
#pragma unroll
  for (int p = 0; p < 4; ++p) {
    const int kl = p * 16 + tr;
    const float4 v = *(const float4*)(w + (size_t)(k0 + kl) * HH + n0 + tc * 4);
    const u32 pk = cvt4_fp8(v.x, v.y, v.z, v.w);
    tile[tc * 4 + 0][kl] = (u8)(pk);
    tile[tc * 4 + 1][kl] = (u8)(pk >> 8);
    tile[tc * 4 + 2][kl] = (u8)(pk >> 16);
    tile[tc * 4 + 3][kl] = (u8)(pk >> 24);
  }
  __syncthreads();
  const int jr = t >> 2;
  const int kc = (t & 3) * 16;
  uint4 ov;
  ov.x = *(const u32*)&tile[jr][kc + 0];
  ov.y = *(const u32*)&tile[jr][kc + 4];
  ov.z = *(const u32*)&tile[jr][kc + 8];
  ov.w = *(const u32*)&tile[jr][kc + 12];
  *(uint4*)(wq + (size_t)(n0 + jr) * HH + k0 + kc) = ov;
}

__device__ __forceinline__ float wred_sum(float v) {
#pragma unroll
  for (int o = 32; o; o >>= 1) v += __shfl_down(v, o, 64);
  return v;
}
__device__ __forceinline__ float wred_max(float v) {
#pragma unroll
  for (int o = 32; o; o >>= 1) v = fmaxf(v, __shfl_down(v, o, 64));
  return v;
}

// MODE 0: src=x, write resid=sqrt(x), quantize rmsnorm(x,nw) -> qout,sout
// MODE 1: src=resid, quantize rmsnorm(resid,nw) -> qout,sout
// MODE 2: src=resid, write y=rmsnorm(resid,nw) fp32 -> yout
template <int MODE>
__global__ __launch_bounds__(256) void knorm(const float* __restrict__ src,
                                             const float* __restrict__ nw,
                                             float* __restrict__ resid_out,
                                             u8* __restrict__ qout,
                                             float* __restrict__ sout,
                                             float* __restrict__ yout) {
  __shared__ float red[4];
  __shared__ float redm[4];
  const int row = blockIdx.x;
  const int t = threadIdx.x;
  const int lane = t & 63, wid = t >> 6;
  const float* rp = src + (size_t)row * HH;

  float4 xv[4];
  float ssq = 0.f;
#pragma unroll
  for (int p = 0; p < 4; ++p) {
    xv[p] = *((const float4*)rp + p * 256 + t);
    ssq += xv[p].x * xv[p].x;
    ssq += xv[p].y * xv[p].y;
    ssq += xv[p].z * xv[p].z;
    ssq += xv[p].w * xv[p].w;
  }
  if (MODE == 0) {
    float* rr = resid_out + (size_t)row * HH;
#pragma unroll
    for (int p = 0; p < 4; ++p) {
      float4 r4;
      r4.x = sqrtf(xv[p].x); r4.y = sqrtf(xv[p].y);
      r4.z = sqrtf(xv[p].z); r4.w = sqrtf(xv[p].w);
      *((float4*)rr + p * 256 + t) = r4;
    }
  }
  ssq = wred_sum(ssq);
  if (lane == 0) red[wid] = ssq;
  __syncthreads();
  const float ms = (((red[0] + red[1]) + red[2]) + red[3]) * (1.0f / HH);
  const float inv = 1.0f / sqrtf(ms + 1e-6f);

  float y[16];
  float amax = 0.f;
#pragma unroll
  for (int p = 0; p < 4; ++p) {
    const float4 wv = *((const float4*)nw + p * 256 + t);
    y[p * 4 + 0] = (xv[p].x * inv) * wv.x;
    y[p * 4 + 1] = (xv[p].y * inv) * wv.y;
    y[p * 4 + 2] = (xv[p].z * inv) * wv.z;
    y[p * 4 + 3] = (xv[p].w * inv) * wv.w;
    amax = fmaxf(amax, fabsf(y[p * 4 + 0]));
    amax = fmaxf(amax, fabsf(y[p * 4 + 1]));
    amax = fmaxf(amax, fabsf(y[p * 4 + 2]));
    amax = fmaxf(amax, fabsf(y[p * 4 + 3]));
  }

  if (MODE == 2) {
    float* yp = yout + (size_t)row * HH;
#pragma unroll
    for (int p = 0; p < 4; ++p) {
      float4 o;
      o.x = y[p * 4 + 0]; o.y = y[p * 4 + 1];
      o.z = y[p * 4 + 2]; o.w = y[p * 4 + 3];
      *((float4*)yp + p * 256 + t) = o;
    }
    return;
  }

  amax = wred_max(amax);
  if (lane == 0) redm[wid] = amax;
  __syncthreads();
  const float bmax = fmaxf(fmaxf(redm[0], redm[1]), fmaxf(redm[2], redm[3]));
  const float sval = fmaxf(bmax / 448.0f, 1e-10f);  // ref: max|y|/448, floor 1e-10

  u32* qp = (u32*)(qout + (size_t)row * HH);
#pragma unroll
  for (int p = 0; p < 4; ++p) {
    float q0 = fminf(fmaxf(y[p * 4 + 0] / sval, -448.f), 448.f);
    float q1 = fminf(fmaxf(y[p * 4 + 1] / sval, -448.f), 448.f);
    float q2 = fminf(fmaxf(y[p * 4 + 2] / sval, -448.f), 448.f);
    float q3 = fminf(fmaxf(y[p * 4 + 3] / sval, -448.f), 448.f);
    qp[p * 256 + t] = cvt4_fp8(q0, q1, q2, q3);
  }
  if (t == 0) sout[row] = sval;
}

// ---- fp8 GEMM via MX-scaled MFMA (unit scales => exact fp8 matmul at 2x rate)
// C[t,j] = sum_k Aq[t,k]*Bq[j,k]; resid[t,j] += C*s[t]*wsc[j]
// m201-style phase schedule. 256x256 tile, BK=64, 8 waves (2Mx4N),
// wave-tile 128x64 = 4x2 frags of 32x32x64. LDS: 3-buffer ring, 32KB/buffer
// (B panel @0, A panel @16KB) = 96KB, 1 block/CU. Prefetch 2 K-tiles.
// Per K-tile: 4 phases; phase m = { ds_read frags (ph0: bv0,bv1,av0 = 6 b128;
// ph1-3: av_m = 2 b128) || stage 1 unit (8KB half-panel, 1 gl_lds/thread) ->
// barrier -> lgkmcnt(0)+sched_barrier -> setprio(1) -> mfma acc[m][0],[1]
// -> setprio(0) -> barrier }.  Staging order = consumption order (B-lo,B-hi,
// A-lo,A-hi), tile it+2 into buf[(it+2)%3]; ONE counted vmcnt(4) per K-tile
// at ph3 (in flight = tiles it+1,it+2 = 8 units; wait leaves newest 4).
// Ring hazards: buf[(it+2)%3] last read as tile it-1 during iter it-1, all
// reads complete before its ph3 end-barrier -> staging at iter it is safe;
// tile it's data landed via each wave's own vmcnt at iter it-1 ph3 + barrier.
// Frag layout (32x32x64 f8f6f4): lane l -> row/col = l&31, k = (l>>5)*32+byte.
// C/D: col=lane&31, row=(reg&3)+8*(reg>>2)+4*(lane>>5)  [HW-verified m74/m101].
__global__ __launch_bounds__(512) void kgemm(const u8* __restrict__ Aq,
                                             const u8* __restrict__ Bq,
                                             const float* __restrict__ srow,
                                             const float* __restrict__ wsc,
                                             float* __restrict__ resid) {
  constexpr int K = HH, N = HH;
  constexpr int NT = K / 64;  // 64
  __shared__ __align__(16) u8 sm[3][32768];  // ring: B@0 (16KB), A@16384 (16KB)

  // grouped XCD swizzle: 1024 blocks over 64(tm) x 16(tn); 2x2 tile groups
  // per XCD -> A 2MB + B 2MB = 4MB working set resident in the 4MB L2.
  const int bidraw = blockIdx.x;
  const int xcd = bidraw & 7;
  const int c = bidraw >> 3;            // 0..127
  const int g = c >> 2;                 // 0..31
  const int gr = g >> 3, gc = g & 7;    // 4 x 8 grid of groups
  const int gm = (c >> 1) & 1, gn = c & 1;
  const int tm = xcd * 8 + gr * 2 + gm;  // 0..63
  const int tn = gc * 2 + gn;            // 0..15
  const int row0 = tm * 256, col0 = tn * 256;

  const int t = threadIdx.x;
  const int lane = t & 63, wid = t >> 6;
  const int wm = wid >> 2, wn = wid & 3;  // wave-tile rows wm*128, cols wn*64
  const int rl32 = lane & 31, hi = lane >> 5;

  f32x16 acc[4][2];
#pragma unroll
  for (int m = 0; m < 4; ++m)
#pragma unroll
    for (int n = 0; n < 2; ++n) acc[m][n] = (f32x16)0.f;

  // staging: one 8KB half-panel unit per phase; thread t loads 16B of it.
  const int sr = t >> 2;                      // 0..127 row within half-panel
  const int scb = (t & 3) ^ ((sr >> 1) & 3);  // inverse-swizzled source block
  const int gBlo = (col0 + sr) * K + scb * 16;
  const int gBhi = (col0 + 128 + sr) * K + scb * 16;
  const int gAlo = (row0 + sr) * K + scb * 16;
  const int gAhi = (row0 + 128 + sr) * K + scb * 16;
  const int dst = t * 16;

  // fragment read offsets within a buffer (16B-block swizzle cb ^= (r>>1)&3)
  int aro[4][2], bro[2][2];
#pragma unroll
  for (int m = 0; m < 4; ++m) {
    const int r = wm * 128 + m * 32 + rl32;
    const int swz = (r >> 1) & 3;
    aro[m][0] = 16384 + r * 64 + ((hi * 2) ^ swz) * 16;
    aro[m][1] = 16384 + r * 64 + ((hi * 2 + 1) ^ swz) * 16;
  }
#pragma unroll
  for (int n = 0; n < 2; ++n) {
    const int r = wn * 64 + n * 32 + rl32;
    const int swz = (r >> 1) & 3;
    bro[n][0] = r * 64 + ((hi * 2) ^ swz) * 16;
    bro[n][1] = r * 64 + ((hi * 2 + 1) ^ swz) * 16;
  }

  // prologue: stage tile 0 -> buf0, tile 1 -> buf1 (issue order = consume order)
  gl_lds16(Bq + gBlo, sm[0] + dst);
  gl_lds16(Bq + gBhi, sm[0] + 8192 + dst);
  gl_lds16(Aq + gAlo, sm[0] + 16384 + dst);
  gl_lds16(Aq + gAhi, sm[0] + 24576 + dst);
  gl_lds16(Bq + gBlo + 64, sm[1] + dst);
  gl_lds16(Bq + gBhi + 64, sm[1] + 8192 + dst);
  gl_lds16(Aq + gAlo + 64, sm[1] + 16384 + dst);
  gl_lds16(Aq + gAhi + 64, sm[1] + 24576 + dst);
  asm volatile("s_waitcnt vmcnt(4)" ::: "memory");  // tile 0 landed; tile 1 flying
  __builtin_amdgcn_s_barrier();
  __builtin_amdgcn_sched_barrier(0);

  for (int it = 0; it < NT; ++it) {
    const u8* sb = sm[it % 3];
    u8* db = sm[(it + 2) % 3];
    const bool st = (it + 2 < NT);
    const int ko = (it + 2) * 64;
    i32x8 bv0, bv1;

    // ---- phase 0: m=0 (reads bv0, bv1, av0) ----
    {
      bv0 = ld32B(sb + bro[0][0], sb + bro[0][1]);
      bv1 = ld32B(sb + bro[1][0], sb + bro[1][1]);
      const i32x8 av = ld32B(sb + aro[0][0], sb + aro[0][1]);
      if (st) gl_lds16(Bq + gBlo + ko, db + dst);
      __builtin_amdgcn_sched_barrier(0);
      __builtin_amdgcn_s_barrier();
      asm volatile("s_waitcnt lgkmcnt(0)" ::: "memory");
      __builtin_amdgcn_sched_barrier(0);
      __builtin_amdgcn_s_setprio(1);
      acc[0][0] = __builtin_amdgcn_mfma_scale_f32_32x32x64_f8f6f4(
          av, bv0, acc[0][0], 0, 0, 0, 0x7f7f7f7f, 0, 0x7f7f7f7f);
      acc[0][1] = __builtin_amdgcn_mfma_scale_f32_32x32x64_f8f6f4(
          av, bv1, acc[0][1], 0, 0, 0, 0x7f7f7f7f, 0, 0x7f7f7f7f);
      __builtin_amdgcn_s_setprio(0);
      __builtin_amdgcn_sched_barrier(0);
      __builtin_amdgcn_s_barrier();
    }
    // ---- phase 1: m=1 ----
    {
      const i32x8 av = ld32B(sb + aro[1][0], sb + aro[1][1]);
      if (st) gl_lds16(Bq + gBhi + ko, db + 8192 + dst);
      __builtin_amdgcn_sched_barrier(0);
      __builtin_amdgcn_s_barrier();
      asm volatile("s_waitcnt lgkmcnt(0)" ::: "memory");
      __builtin_amdgcn_sched_barrier(0);
      __builtin_amdgcn_s_setprio(1);
      acc[1][0] = __builtin_amdgcn_mfma_scale_f32_32x32x64_f8f6f4(
          av, bv0, acc[1][0], 0, 0, 0, 0x7f7f7f7f, 0, 0x7f7f7f7f);
      acc[1][1] = __builtin_amdgcn_mfma_scale_f32_32x32x64_f8f6f4(
          av, bv1, acc[1][1], 0, 0, 0, 0x7f7f7f7f, 0, 0x7f7f7f7f);
      __builtin_amdgcn_s_setprio(0);
      __builtin_amdgcn_sched_barrier(0);
      __builtin_amdgcn_s_barrier();
    }
    // ---- phase 2: m=2 ----
    {
      const i32x8 av = ld32B(sb + aro[2][0], sb + aro[2][1]);
      if (st) gl_lds16(Aq + gAlo + ko, db + 16384 + dst);
      __builtin_amdgcn_sched_barrier(0);
      __builtin_amdgcn_s_barrier();
      asm volatile("s_waitcnt lgkmcnt(0)" ::: "memory");
      __builtin_amdgcn_sched_barrier(0);
      __builtin_amdgcn_s_setprio(1);
      acc[2][0] = __builtin_amdgcn_mfma_scale_f32_32x32x64_f8f6f4(
          av, bv0, acc[2][0], 0, 0, 0, 0x7f7f7f7f, 0, 0x7f7f7f7f);
      acc[2][1] = __builtin_amdgcn_mfma_scale_f32_32x32x64_f8f6f4(
          av, bv1, acc[2][1], 0, 0, 0, 0x7f7f7f7f, 0, 0x7f7f7f7f);
      __builtin_amdgcn_s_setprio(0);
      __builtin_amdgcn_sched_barrier(0);
      __builtin_amdgcn_s_barrier();
    }
    // ---- phase 3: m=3 (+ the single per-tile counted vmcnt) ----
    {
      const i32x8 av = ld32B(sb + aro[3][0], sb + aro[3][1]);
      if (st) gl_lds16(Aq + gAhi + ko, db + 24576 + dst);
      __builtin_amdgcn_sched_barrier(0);
      __builtin_amdgcn_s_barrier();
      asm volatile("s_waitcnt lgkmcnt(0)" ::: "memory");
      __builtin_amdgcn_sched_barrier(0);
      __builtin_amdgcn_s_setprio(1);
      acc[3][0] = __builtin_amdgcn_mfma_scale_f32_32x32x64_f8f6f4(
          av, bv0, acc[3][0], 0, 0, 0, 0x7f7f7f7f, 0, 0x7f7f7f7f);
      acc[3][1] = __builtin_amdgcn_mfma_scale_f32_32x32x64_f8f6f4(
          av, bv1, acc[3][1], 0, 0, 0, 0x7f7f7f7f, 0, 0x7f7f7f7f);
      __builtin_amdgcn_s_setprio(0);
      // tile it+1 must be fully landed before iter it+1's phase-0 reads.
      if (st) {
        asm volatile("s_waitcnt vmcnt(4)" ::: "memory");  // leave tile it+2 flying
      } else {
        asm volatile("s_waitcnt vmcnt(0)" ::: "memory");  // drain tail
      }
      __builtin_amdgcn_sched_barrier(0);
      __builtin_amdgcn_s_barrier();
    }
  }

  // epilogue: resid += (acc * s_token) * wscale_col
  const int cc = rl32;
  const int rb = hi * 4;
  float wvv[2];
#pragma unroll
  for (int n = 0; n < 2; ++n) wvv[n] = wsc[col0 + wn * 64 + n * 32 + cc];
#pragma unroll
  for (int m = 0; m < 4; ++m) {
#pragma unroll
    for (int g2 = 0; g2 < 4; ++g2) {
#pragma unroll
      for (int j = 0; j < 4; ++j) {
        const int row = row0 + wm * 128 + m * 32 + g2 * 8 + rb + j;
        const float sv = srow[row];
#pragma unroll
        for (int n = 0; n < 2; ++n) {
          const int col = col0 + wn * 64 + n * 32 + cc;
          const size_t idx = (size_t)row * N + col;
          resid[idx] = resid[idx] + (acc[m][n][g2 * 4 + j] * sv) * wvv[n];
        }
      }
    }
  }
}

extern "C" void kernel_launch(void* const* d_in, const int* in_sizes, int n_in,
                              void* d_out, int out_size, void* d_ws, size_t ws_size,
                              hipStream_t stream) {
  const float* x   = (const float*)d_in[0];
  const float* nw0 = (const float*)d_in[1];
  const float* nw1 = (const float*)d_in[2];
  const float* nw2 = (const float*)d_in[3];
  const float* w0  = (const float*)d_in[4];
  const float* w1  = (const float*)d_in[5];
  const float* ws0 = (const float*)d_in[6];
  const float* ws1 = (const float*)d_in[7];
  float* out = (float*)d_out;

  // workspace: q (T*H fp8) | w0q (H*H fp8) | w1q (H*H fp8) | s (T fp32)  ~= 96.1 MiB
  u8* q = (u8*)d_ws;
  u8* w0q = q + (size_t)TT * HH;
  u8* w1q = w0q + (size_t)HH * HH;
  float* sbuf = (float*)(w1q + (size_t)HH * HH);

  dim3 wg(HH / 64, HH / 64);
  kwquant<<<wg, 256, 0, stream>>>(w0, w0q);
  kwquant<<<wg, 256, 0, stream>>>(w1, w1q);

  const int gblocks = (TT / 256) * (HH / 256);  // 1024
  knorm<0><<<TT, 256, 0, stream>>>(x, nw0, out, q, sbuf, nullptr);
  kgemm<<<gblocks, 512, 0, stream>>>(q, w0q, sbuf, ws0, out);
  knorm<1><<<TT, 256, 0, stream>>>(out, nw1, nullptr, q, sbuf, nullptr);
  kgemm<<<gblocks, 512, 0, stream>>>(q, w1q, sbuf, ws1, out);
  knorm<2><<<TT, 256, 0, stream>>>(out, nw2, nullptr, nullptr, nullptr, out);
}

// Round 15
// 1205.547 us; speedup vs baseline: 1.2503x; 1.0084x over previous
//
#include <hip/hip_runtime.h>
#include <stdint.h>

#define TT 16384
#define HH 4096

typedef uint8_t u8;
typedef uint32_t u32;
typedef __attribute__((ext_vector_type(16))) float f32x16;
typedef __attribute__((ext_vector_type(8))) int i32x8;

// ---- fp8 e4m3 (OCP) pack: 4 floats -> 4 bytes, RNE, saturating ----
__device__ __forceinline__ u32 cvt4_fp8(float a, float b, float c, float d) {
  u32 v = 0;
  v = __builtin_amdgcn_cvt_pk_fp8_f32(a, b, v, false);  // low word
  v = __builtin_amdgcn_cvt_pk_fp8_f32(c, d, v, true);   // high word
  return v;
}

__device__ __forceinline__ void gl_lds16(const void* g, void* l) {
  __builtin_amdgcn_global_load_lds(
      (const __attribute__((address_space(1))) void*)g,
      (__attribute__((address_space(3))) void*)l, 16, 0, 0);
}

struct A2 { uint4 lo, hi; };
__device__ __forceinline__ A2 ldA32(const u8* p) {
  A2 r;
  r.lo = ((const uint4*)p)[0];
  r.hi = ((const uint4*)p)[1];
  return r;
}
__device__ __forceinline__ i32x8 packA(const A2& a) {
  i32x8 r;
  r[0] = (int)a.lo.x; r[1] = (int)a.lo.y; r[2] = (int)a.lo.z; r[3] = (int)a.lo.w;
  r[4] = (int)a.hi.x; r[5] = (int)a.hi.y; r[6] = (int)a.hi.z; r[7] = (int)a.hi.w;
  return r;
}
__device__ __forceinline__ i32x8 ld32B(const u8* p0, const u8* p1) {
  const uint4 a = *(const uint4*)p0;
  const uint4 b = *(const uint4*)p1;
  i32x8 r;
  r[0] = (int)a.x; r[1] = (int)a.y; r[2] = (int)a.z; r[3] = (int)a.w;
  r[4] = (int)b.x; r[5] = (int)b.y; r[6] = (int)b.z; r[7] = (int)b.w;
  return r;
}

// ---- weight quantize + transpose: w[K][N] fp32 (on fp8 grid) -> wq[N][K] fp8 (plain)
__global__ __launch_bounds__(256) void kwquant(const float* __restrict__ w,
                                               u8* __restrict__ wq) {
  __shared__ __align__(16) u8 tile[64][68];
  const int n0 = blockIdx.x * 64;
  const int k0 = blockIdx.y * 64;
  const int t = threadIdx.x;
  const int tr = t >> 4, tc = t & 15;
#pragma unroll
  for (int p = 0; p < 4; ++p) {
    const int kl = p * 16 + tr;
    const float4 v = *(const float4*)(w + (size_t)(k0 + kl) * HH + n0 + tc * 4);
    const u32 pk = cvt4_fp8(v.x, v.y, v.z, v.w);
    tile[tc * 4 + 0][kl] = (u8)(pk);
    tile[tc * 4 + 1][kl] = (u8)(pk >> 8);
    tile[tc * 4 + 2][kl] = (u8)(pk >> 16);
    tile[tc * 4 + 3][kl] = (u8)(pk >> 24);
  }
  __syncthreads();
  const int jr = t >> 2;
  const int kc = (t & 3) * 16;
  uint4 ov;
  ov.x = *(const u32*)&tile[jr][kc + 0];
  ov.y = *(const u32*)&tile[jr][kc + 4];
  ov.z = *(const u32*)&tile[jr][kc + 8];
  ov.w = *(const u32*)&tile[jr][kc + 12];
  *(uint4*)(wq + (size_t)(n0 + jr) * HH + k0 + kc) = ov;
}

__device__ __forceinline__ float wred_sum(float v) {
#pragma unroll
  for (int o = 32; o; o >>= 1) v += __shfl_down(v, o, 64);
  return v;
}
__device__ __forceinline__ float wred_max(float v) {
#pragma unroll
  for (int o = 32; o; o >>= 1) v = fmaxf(v, __shfl_down(v, o, 64));
  return v;
}

// MODE 0: src=x, write resid=sqrt(x), quantize rmsnorm(x,nw) -> qout (A-frag-major), sout
// MODE 1: src=resid, quantize rmsnorm(resid,nw) -> qout (A-frag-major), sout
// MODE 2: src=resid, write y=rmsnorm(resid,nw) fp32 -> yout
// A-fragment-major layout: dword address for (row, dword d=k/4):
//   (rp*64 + kp)*512 + (rl + 32*hi)*8 + (d&7)
//   rp=row>>5, rl=row&31, kp=d>>4, hi=(d>>3)&1
// so a GEMM wave's 32B/lane fragment is 2048 contiguous bytes per (rp,kp).
template <int MODE>
__global__ __launch_bounds__(256) void knorm(const float* __restrict__ src,
                                             const float* __restrict__ nw,
                                             float* __restrict__ resid_out,
                                             u8* __restrict__ qout,
                                             float* __restrict__ sout,
                                             float* __restrict__ yout) {
  __shared__ float red[4];
  __shared__ float redm[4];
  const int row = blockIdx.x;
  const int t = threadIdx.x;
  const int lane = t & 63, wid = t >> 6;
  const float* rp_ = src + (size_t)row * HH;

  float4 xv[4];
  float ssq = 0.f;
#pragma unroll
  for (int p = 0; p < 4; ++p) {
    xv[p] = *((const float4*)rp_ + p * 256 + t);
    ssq += xv[p].x * xv[p].x;
    ssq += xv[p].y * xv[p].y;
    ssq += xv[p].z * xv[p].z;
    ssq += xv[p].w * xv[p].w;
  }
  if (MODE == 0) {
    float* rr = resid_out + (size_t)row * HH;
#pragma unroll
    for (int p = 0; p < 4; ++p) {
      float4 r4;
      r4.x = sqrtf(xv[p].x); r4.y = sqrtf(xv[p].y);
      r4.z = sqrtf(xv[p].z); r4.w = sqrtf(xv[p].w);
      *((float4*)rr + p * 256 + t) = r4;
    }
  }
  ssq = wred_sum(ssq);
  if (lane == 0) red[wid] = ssq;
  __syncthreads();
  const float ms = (((red[0] + red[1]) + red[2]) + red[3]) * (1.0f / HH);
  const float inv = 1.0f / sqrtf(ms + 1e-6f);

  float y[16];
  float amax = 0.f;
#pragma unroll
  for (int p = 0; p < 4; ++p) {
    const float4 wv = *((const float4*)nw + p * 256 + t);
    y[p * 4 + 0] = (xv[p].x * inv) * wv.x;
    y[p * 4 + 1] = (xv[p].y * inv) * wv.y;
    y[p * 4 + 2] = (xv[p].z * inv) * wv.z;
    y[p * 4 + 3] = (xv[p].w * inv) * wv.w;
    amax = fmaxf(amax, fabsf(y[p * 4 + 0]));
    amax = fmaxf(amax, fabsf(y[p * 4 + 1]));
    amax = fmaxf(amax, fabsf(y[p * 4 + 2]));
    amax = fmaxf(amax, fabsf(y[p * 4 + 3]));
  }

  if (MODE == 2) {
    float* yp = yout + (size_t)row * HH;
#pragma unroll
    for (int p = 0; p < 4; ++p) {
      float4 o;
      o.x = y[p * 4 + 0]; o.y = y[p * 4 + 1];
      o.z = y[p * 4 + 2]; o.w = y[p * 4 + 3];
      *((float4*)yp + p * 256 + t) = o;
    }
    return;
  }

  amax = wred_max(amax);
  if (lane == 0) redm[wid] = amax;
  __syncthreads();
  const float bmax = fmaxf(fmaxf(redm[0], redm[1]), fmaxf(redm[2], redm[3]));
  const float sval = fmaxf(bmax / 448.0f, 1e-10f);  // ref: max|y|/448, floor 1e-10

  u32* qA = (u32*)qout;
  const int rp5 = row >> 5, rl5 = row & 31;
#pragma unroll
  for (int p = 0; p < 4; ++p) {
    float q0 = fminf(fmaxf(y[p * 4 + 0] / sval, -448.f), 448.f);
    float q1 = fminf(fmaxf(y[p * 4 + 1] / sval, -448.f), 448.f);
    float q2 = fminf(fmaxf(y[p * 4 + 2] / sval, -448.f), 448.f);
    float q3 = fminf(fmaxf(y[p * 4 + 3] / sval, -448.f), 448.f);
    const int d = p * 256 + t;
    const size_t dw = (size_t)(rp5 * 64 + (d >> 4)) * 512 +
                      (size_t)(rl5 + 32 * ((d >> 3) & 1)) * 8 + (d & 7);
    qA[dw] = cvt4_fp8(q0, q1, q2, q3);
  }
  if (t == 0) sout[row] = sval;
}

// ---- fp8 GEMM via MX-scaled MFMA (unit scales => exact fp8 matmul at 2x rate)
// C[t,j] = sum_k Aq[t,k]*Bq[j,k]; resid[t,j] += C*s[t]*wsc[j]
// R15: R11 skeleton with A-coalescing FIXED via fragment-major global layout.
// A: wave-private frags loaded global->VGPR, fully coalesced (2x 1KB insts per
//    frag), double-buffered a0/a1 across unroll-2 loop (static reg sets).
// B: R10-verified LDS ring (3 buffers x 8KB, prefetch-2), row-major 64B rows,
//    16B-block swizzle cb ^= (r>>1)&3 (inverse pre-applied on global source).
// vmcnt ledger (A-loads + B gl_lds both count): at iter-j wait for B(j)
// [staged at j-2], younger ops = (A 4 + B 2) x 2 iters = 12 steady;
// tails: j=NT-2 -> 10, j=NT-1 -> 4. Compiler auto-waits A-reg uses.
// Grouped XCD swizzle (R10, verified): 4x4 tile groups -> 4MB per-XCD L2 set.
// Frag layout (32x32x64 f8f6f4): lane l -> row/col = l&31, k = (l>>5)*32+byte.
// C/D: col=lane&31, row=(reg&3)+8*(reg>>2)+4*(lane>>5)  [HW-verified m74/m101].
__global__ __launch_bounds__(256) void kgemm(const u8* __restrict__ Aq,
                                             const u8* __restrict__ Bq,
                                             const float* __restrict__ srow,
                                             const float* __restrict__ wsc,
                                             float* __restrict__ resid) {
  constexpr int K = HH, N = HH;
  constexpr int NT = K / 64;  // 64 (even)
  __shared__ __align__(16) u8 smB[3 * 128 * 64];  // 24 KiB, B-only ring

  // grouped 2-level swizzle (R10): 4x4 (tm,tn) groups per XCD -> 4 MB L2 set
  const int bidraw = blockIdx.x;
  const int xcd = bidraw & 7;
  const int c = bidraw >> 3;            // 0..511
  const int g = c >> 4;                 // 32 groups of 16 blocks
  const int gr = g >> 3, gc = g & 7;    // 4 x 8 grid of groups
  const int gm = (c >> 2) & 3, gn = c & 3;
  const int tm = xcd * 16 + gr * 4 + gm;  // 0..127
  const int tn = gc * 4 + gn;             // 0..31
  const int row0 = tm * 128, col0 = tn * 128;

  const int t = threadIdx.x;
  const int lane = t & 63, wid = t >> 6;
  const int wr = wid >> 1, wc = wid & 1;
  const int rl32 = lane & 31, hi = lane >> 5;

  f32x16 acc[2][2];
#pragma unroll
  for (int m = 0; m < 2; ++m)
#pragma unroll
    for (int n = 0; n < 2; ++n) acc[m][n] = (f32x16)0.f;

  // A fragment-major pointers: frag (m) panel rp = tm*4 + wr*2 + m;
  // lane's 32B at (rp*64 + kp)*2048 + lane*32. Advance +2048/K-tile.
  const u8* apA[2];
#pragma unroll
  for (int m = 0; m < 2; ++m) {
    const int rp = tm * 4 + wr * 2 + m;
    apA[m] = Aq + (size_t)(rp * 64) * 2048 + lane * 32;
  }

  // B staging addresses (16B-block swizzle cb ^= (r>>1)&3, inverse on source)
  int boffg[2], ldso[2];
#pragma unroll
  for (int p = 0; p < 2; ++p) {
    const int off = (wid * 2 + p) * 1024 + lane * 16;
    const int r = off >> 6;
    const int cb = ((off >> 4) & 3) ^ ((r >> 1) & 3);
    boffg[p] = (col0 + r) * K + cb * 16;
    ldso[p] = off;
  }

  // B fragment read offsets within a buffer
  int bro[2][2];
#pragma unroll
  for (int n = 0; n < 2; ++n) {
    const int r = wc * 64 + n * 32 + rl32;
    const int swz = (r >> 1) & 3;
    bro[n][0] = r * 64 + ((hi * 2) ^ swz) * 16;
    bro[n][1] = r * 64 + ((hi * 2 + 1) ^ swz) * 16;
  }

  // prologue: stage B(0)->buf0, B(1)->buf1; load A(0) into set a0
#pragma unroll
  for (int p = 0; p < 2; ++p) gl_lds16(Bq + boffg[p], smB + ldso[p]);
#pragma unroll
  for (int p = 0; p < 2; ++p) gl_lds16(Bq + boffg[p] + 64, smB + 8192 + ldso[p]);
  A2 a0[2], a1[2];
#pragma unroll
  for (int m = 0; m < 2; ++m) a0[m] = ldA32(apA[m]);

  int bc = 0;  // compute buffer for even iter of the pair
  for (int it = 0; it < NT; it += 2) {
    const int b_even = bc;
    const int b_odd = (bc == 2) ? 0 : bc + 1;
    const int b_st0 = (b_odd == 2) ? 0 : b_odd + 1;  // stage target B(it+2)
    const int b_st1 = b_even;                        // stage target B(it+3)

    // ---- even iteration: compute tile it with a0 ----
    if (it + 1 < NT) {
#pragma unroll
      for (int m = 0; m < 2; ++m) a1[m] = ldA32(apA[m] + (size_t)(it + 1) * 2048);
    }
    if (it + 2 < NT) {
      const size_t ko = (size_t)(it + 2) * 64;
#pragma unroll
      for (int p = 0; p < 2; ++p)
        gl_lds16(Bq + boffg[p] + ko, smB + b_st0 * 8192 + ldso[p]);
      asm volatile("s_waitcnt vmcnt(12)" ::: "memory");  // B(it) landed
    } else {
      asm volatile("s_waitcnt vmcnt(10)" ::: "memory");  // tail (it=NT-2)
    }
    __builtin_amdgcn_s_barrier();
    __builtin_amdgcn_sched_barrier(0);
    {
      const u8* sB = smB + b_even * 8192;
      const i32x8 bv0 = ld32B(sB + bro[0][0], sB + bro[0][1]);
      const i32x8 bv1 = ld32B(sB + bro[1][0], sB + bro[1][1]);
      __builtin_amdgcn_s_setprio(1);
#pragma unroll
      for (int m = 0; m < 2; ++m) {
        const i32x8 av = packA(a0[m]);
        acc[m][0] = __builtin_amdgcn_mfma_scale_f32_32x32x64_f8f6f4(
            av, bv0, acc[m][0], 0, 0, 0, 0x7f7f7f7f, 0, 0x7f7f7f7f);
        acc[m][1] = __builtin_amdgcn_mfma_scale_f32_32x32x64_f8f6f4(
            av, bv1, acc[m][1], 0, 0, 0, 0x7f7f7f7f, 0, 0x7f7f7f7f);
      }
      __builtin_amdgcn_s_setprio(0);
    }
    __builtin_amdgcn_sched_barrier(0);
    __builtin_amdgcn_s_barrier();

    // ---- odd iteration: compute tile it+1 with a1 ----
    if (it + 2 < NT) {
#pragma unroll
      for (int m = 0; m < 2; ++m) a0[m] = ldA32(apA[m] + (size_t)(it + 2) * 2048);
    }
    if (it + 3 < NT) {
      const size_t ko = (size_t)(it + 3) * 64;
#pragma unroll
      for (int p = 0; p < 2; ++p)
        gl_lds16(Bq + boffg[p] + ko, smB + b_st1 * 8192 + ldso[p]);
      asm volatile("s_waitcnt vmcnt(12)" ::: "memory");  // B(it+1) landed
    } else {
      asm volatile("s_waitcnt vmcnt(4)" ::: "memory");   // tail (it+1=NT-1)
    }
    __builtin_amdgcn_s_barrier();
    __builtin_amdgcn_sched_barrier(0);
    {
      const u8* sB = smB + b_odd * 8192;
      const i32x8 bv0 = ld32B(sB + bro[0][0], sB + bro[0][1]);
      const i32x8 bv1 = ld32B(sB + bro[1][0], sB + bro[1][1]);
      __builtin_amdgcn_s_setprio(1);
#pragma unroll
      for (int m = 0; m < 2; ++m) {
        const i32x8 av = packA(a1[m]);
        acc[m][0] = __builtin_amdgcn_mfma_scale_f32_32x32x64_f8f6f4(
            av, bv0, acc[m][0], 0, 0, 0, 0x7f7f7f7f, 0, 0x7f7f7f7f);
        acc[m][1] = __builtin_amdgcn_mfma_scale_f32_32x32x64_f8f6f4(
            av, bv1, acc[m][1], 0, 0, 0, 0x7f7f7f7f, 0, 0x7f7f7f7f);
      }
      __builtin_amdgcn_s_setprio(0);
    }
    __builtin_amdgcn_sched_barrier(0);
    __builtin_amdgcn_s_barrier();

    bc = (bc + 2 > 2) ? bc - 1 : bc + 2;  // (bc + 2) % 3
  }

  // epilogue: resid += (acc * s_token) * wscale_col
  const int cc = rl32;
  const int rb = hi * 4;
  float wvv[2];
#pragma unroll
  for (int n = 0; n < 2; ++n) wvv[n] = wsc[col0 + wc * 64 + n * 32 + cc];
#pragma unroll
  for (int m = 0; m < 2; ++m) {
#pragma unroll
    for (int g2 = 0; g2 < 4; ++g2) {
#pragma unroll
      for (int j = 0; j < 4; ++j) {
        const int row = row0 + wr * 64 + m * 32 + g2 * 8 + rb + j;
        const float sv = srow[row];
#pragma unroll
        for (int n = 0; n < 2; ++n) {
          const int col = col0 + wc * 64 + n * 32 + cc;
          const size_t idx = (size_t)row * N + col;
          resid[idx] = resid[idx] + (acc[m][n][g2 * 4 + j] * sv) * wvv[n];
        }
      }
    }
  }
}

extern "C" void kernel_launch(void* const* d_in, const int* in_sizes, int n_in,
                              void* d_out, int out_size, void* d_ws, size_t ws_size,
                              hipStream_t stream) {
  const float* x   = (const float*)d_in[0];
  const float* nw0 = (const float*)d_in[1];
  const float* nw1 = (const float*)d_in[2];
  const float* nw2 = (const float*)d_in[3];
  const float* w0  = (const float*)d_in[4];
  const float* w1  = (const float*)d_in[5];
  const float* ws0 = (const float*)d_in[6];
  const float* ws1 = (const float*)d_in[7];
  float* out = (float*)d_out;

  // workspace: q (T*H fp8, frag-major) | w0q | w1q | s (T fp32)  ~= 96.1 MiB
  u8* q = (u8*)d_ws;
  u8* w0q = q + (size_t)TT * HH;
  u8* w1q = w0q + (size_t)HH * HH;
  float* sbuf = (float*)(w1q + (size_t)HH * HH);

  dim3 wg(HH / 64, HH / 64);
  kwquant<<<wg, 256, 0, stream>>>(w0, w0q);
  kwquant<<<wg, 256, 0, stream>>>(w1, w1q);

  knorm<0><<<TT, 256, 0, stream>>>(x, nw0, out, q, sbuf, nullptr);
  kgemm<<<(TT / 128) * (HH / 128), 256, 0, stream>>>(q, w0q, sbuf, ws0, out);
  knorm<1><<<TT, 256, 0, stream>>>(out, nw1, nullptr, q, sbuf, nullptr);
  kgemm<<<(TT / 128) * (HH / 128), 256, 0, stream>>>(q, w1q, sbuf, ws1, out);
  knorm<2><<<TT, 256, 0, stream>>>(out, nw2, nullptr, nullptr, nullptr, out);
}

// Round 16
// 1133.689 us; speedup vs baseline: 1.3296x; 1.0634x over previous
//
#include <hip/hip_runtime.h>
#include <stdint.h>

#define TT 16384
#define HH 4096

typedef uint8_t u8;
typedef uint32_t u32;
typedef __attribute__((ext_vector_type(16))) float f32x16;
typedef __attribute__((ext_vector_type(8))) int i32x8;

// ---- fp8 e4m3 (OCP) pack: 4 floats -> 4 bytes, RNE, saturating ----
__device__ __forceinline__ u32 cvt4_fp8(float a, float b, float c, float d) {
  u32 v = 0;
  v = __builtin_amdgcn_cvt_pk_fp8_f32(a, b, v, false);  // low word
  v = __builtin_amdgcn_cvt_pk_fp8_f32(c, d, v, true);   // high word
  return v;
}

__device__ __forceinline__ void gl_lds16(const void* g, void* l) {
  __builtin_amdgcn_global_load_lds(
      (const __attribute__((address_space(1))) void*)g,
      (__attribute__((address_space(3))) void*)l, 16, 0, 0);
}

__device__ __forceinline__ i32x8 ld32B(const u8* p0, const u8* p1) {
  const uint4 a = *(const uint4*)p0;
  const uint4 b = *(const uint4*)p1;
  i32x8 r;
  r[0] = (int)a.x; r[1] = (int)a.y; r[2] = (int)a.z; r[3] = (int)a.w;
  r[4] = (int)b.x; r[5] = (int)b.y; r[6] = (int)b.z; r[7] = (int)b.w;
  return r;
}

// ---- weight quantize + transpose: w[K][N] fp32 (on fp8 grid) -> wq[N][K] fp8 (plain)
__global__ __launch_bounds__(256) void kwquant(const float* __restrict__ w,
                                               u8* __restrict__ wq) {
  __shared__ __align__(16) u8 tile[64][68];
  const int n0 = blockIdx.x * 64;
  const int k0 = blockIdx.y * 64;
  const int t = threadIdx.x;
  const int tr = t >> 4, tc = t & 15;
#pragma unroll
  for (int p = 0; p < 4; ++p) {
    const int kl = p * 16 + tr;
    const float4 v = *(const float4*)(w + (size_t)(k0 + kl) * HH + n0 + tc * 4);
    const u32 pk = cvt4_fp8(v.x, v.y, v.z, v.w);
    tile[tc * 4 + 0][kl] = (u8)(pk);
    tile[tc * 4 + 1][kl] = (u8)(pk >> 8);
    tile[tc * 4 + 2][kl] = (u8)(pk >> 16);
    tile[tc * 4 + 3][kl] = (u8)(pk >> 24);
  }
  __syncthreads();
  const int jr = t >> 2;
  const int kc = (t & 3) * 16;
  uint4 ov;
  ov.x = *(const u32*)&tile[jr][kc + 0];
  ov.y = *(const u32*)&tile[jr][kc + 4];
  ov.z = *(const u32*)&tile[jr][kc + 8];
  ov.w = *(const u32*)&tile[jr][kc + 12];
  *(uint4*)(wq + (size_t)(n0 + jr) * HH + k0 + kc) = ov;
}

__device__ __forceinline__ float wred_sum(float v) {
#pragma unroll
  for (int o = 32; o; o >>= 1) v += __shfl_down(v, o, 64);
  return v;
}
__device__ __forceinline__ float wred_max(float v) {
#pragma unroll
  for (int o = 32; o; o >>= 1) v = fmaxf(v, __shfl_down(v, o, 64));
  return v;
}

// MODE 0: src=x, write resid=sqrt(x), quantize rmsnorm(x,nw) -> qout,sout
// MODE 1: src=resid, quantize rmsnorm(resid,nw) -> qout,sout
// MODE 2: src=resid, write y=rmsnorm(resid,nw) fp32 -> yout
template <int MODE>
__global__ __launch_bounds__(256) void knorm(const float* __restrict__ src,
                                             const float* __restrict__ nw,
                                             float* __restrict__ resid_out,
                                             u8* __restrict__ qout,
                                             float* __restrict__ sout,
                                             float* __restrict__ yout) {
  __shared__ float red[4];
  __shared__ float redm[4];
  const int row = blockIdx.x;
  const int t = threadIdx.x;
  const int lane = t & 63, wid = t >> 6;
  const float* rp = src + (size_t)row * HH;

  float4 xv[4];
  float ssq = 0.f;
#pragma unroll
  for (int p = 0; p < 4; ++p) {
    xv[p] = *((const float4*)rp + p * 256 + t);
    ssq += xv[p].x * xv[p].x;
    ssq += xv[p].y * xv[p].y;
    ssq += xv[p].z * xv[p].z;
    ssq += xv[p].w * xv[p].w;
  }
  if (MODE == 0) {
    float* rr = resid_out + (size_t)row * HH;
#pragma unroll
    for (int p = 0; p < 4; ++p) {
      float4 r4;
      r4.x = sqrtf(xv[p].x); r4.y = sqrtf(xv[p].y);
      r4.z = sqrtf(xv[p].z); r4.w = sqrtf(xv[p].w);
      *((float4*)rr + p * 256 + t) = r4;
    }
  }
  ssq = wred_sum(ssq);
  if (lane == 0) red[wid] = ssq;
  __syncthreads();
  const float ms = (((red[0] + red[1]) + red[2]) + red[3]) * (1.0f / HH);
  const float inv = 1.0f / sqrtf(ms + 1e-6f);

  float y[16];
  float amax = 0.f;
#pragma unroll
  for (int p = 0; p < 4; ++p) {
    const float4 wv = *((const float4*)nw + p * 256 + t);
    y[p * 4 + 0] = (xv[p].x * inv) * wv.x;
    y[p * 4 + 1] = (xv[p].y * inv) * wv.y;
    y[p * 4 + 2] = (xv[p].z * inv) * wv.z;
    y[p * 4 + 3] = (xv[p].w * inv) * wv.w;
    amax = fmaxf(amax, fabsf(y[p * 4 + 0]));
    amax = fmaxf(amax, fabsf(y[p * 4 + 1]));
    amax = fmaxf(amax, fabsf(y[p * 4 + 2]));
    amax = fmaxf(amax, fabsf(y[p * 4 + 3]));
  }

  if (MODE == 2) {
    float* yp = yout + (size_t)row * HH;
#pragma unroll
    for (int p = 0; p < 4; ++p) {
      float4 o;
      o.x = y[p * 4 + 0]; o.y = y[p * 4 + 1];
      o.z = y[p * 4 + 2]; o.w = y[p * 4 + 3];
      *((float4*)yp + p * 256 + t) = o;
    }
    return;
  }

  amax = wred_max(amax);
  if (lane == 0) redm[wid] = amax;
  __syncthreads();
  const float bmax = fmaxf(fmaxf(redm[0], redm[1]), fmaxf(redm[2], redm[3]));
  const float sval = fmaxf(bmax / 448.0f, 1e-10f);  // ref: max|y|/448, floor 1e-10

  u32* qp = (u32*)(qout + (size_t)row * HH);
#pragma unroll
  for (int p = 0; p < 4; ++p) {
    float q0 = fminf(fmaxf(y[p * 4 + 0] / sval, -448.f), 448.f);
    float q1 = fminf(fmaxf(y[p * 4 + 1] / sval, -448.f), 448.f);
    float q2 = fminf(fmaxf(y[p * 4 + 2] / sval, -448.f), 448.f);
    float q3 = fminf(fmaxf(y[p * 4 + 3] / sval, -448.f), 448.f);
    qp[p * 256 + t] = cvt4_fp8(q0, q1, q2, q3);
  }
  if (t == 0) sout[row] = sval;
}

// ---- fp8 GEMM via MX-scaled MFMA (unit scales => exact fp8 matmul at 2x rate)
// C[t,j] = sum_k Aq[t,k]*Bq[j,k]; resid[t,j] += C*s[t]*wsc[j]
// R16: R10 shell (128x128 tile, 3-buf ring, prefetch-2, grouped XCD swizzle),
// restructured to cut the verified LDS bottleneck (R10 books: LDS 640cy of a
// 990cy wall):
//  - 2 waves/block (128 thr), wave-tile 128x64 = 4x2 frags: same 16 MFMA per
//    block-iter, LDS reads 32 -> 24 b128 (A frags reused across both waves'
//    n-columns), barrier participants halved.
//  - finer XOR swizzle swz = r&3: each 4-row group covers all 32 banks exactly
//    once per b128 pair (targets the residual 128cy/iter conflict term).
// Staging: 16KB/tile (A 8KB @0, B 8KB @8192); 8 gl_lds/thread/tile (dst =
// p*2048 + t*16, linear). vmcnt ledger: prologue 16; steady stage 8 + wait
// vmcnt(16) (tile it landed, it+1/it+2 in flight); tails 8 -> 0.
// Inner loop spill-safe pattern from R8: bv0,bv1 held; av loaded per-m.
// Frag layout (32x32x64 f8f6f4): lane l -> row/col = l&31, k = (l>>5)*32+byte.
// C/D: col=lane&31, row=(reg&3)+8*(reg>>2)+4*(lane>>5)  [HW-verified m74/m101].
__global__ __launch_bounds__(128) void kgemm(const u8* __restrict__ Aq,
                                             const u8* __restrict__ Bq,
                                             const float* __restrict__ srow,
                                             const float* __restrict__ wsc,
                                             float* __restrict__ resid) {
  constexpr int K = HH, N = HH;
  constexpr int NT = K / 64;  // 64
  __shared__ __align__(16) u8 sm[3][16384];  // ring: A@0 (8KB), B@8192 (8KB)

  // grouped 2-level swizzle (R10): 4x4 (tm,tn) groups per XCD -> 4 MB L2 set
  const int bidraw = blockIdx.x;
  const int xcd = bidraw & 7;
  const int c = bidraw >> 3;            // 0..511
  const int g = c >> 4;                 // 32 groups of 16 blocks
  const int gr = g >> 3, gc = g & 7;    // 4 x 8 grid of groups
  const int gm = (c >> 2) & 3, gn = c & 3;
  const int tm = xcd * 16 + gr * 4 + gm;  // 0..127
  const int tn = gc * 4 + gn;             // 0..31
  const int row0 = tm * 128, col0 = tn * 128;

  const int t = threadIdx.x;
  const int lane = t & 63;
  const int wn = t >> 6;                  // 2 waves: n-halves of the tile
  const int rl32 = lane & 31, hi = lane >> 5;

  f32x16 acc[4][2];
#pragma unroll
  for (int m = 0; m < 4; ++m)
#pragma unroll
    for (int n = 0; n < 2; ++n) acc[m][n] = (f32x16)0.f;

  // staging: 8 units/thread/tile; p<4 -> A panel, p>=4 -> B panel.
  // slot = (p&3)*128 + t in the 512-slot panel; row = slot>>2; source col
  // block = (slot&3) ^ (row&3) (inverse swizzle on global source).
  int goff[8];
#pragma unroll
  for (int p = 0; p < 8; ++p) {
    const int slot = (p & 3) * 128 + t;
    const int r = slot >> 2;
    const int cb = (slot & 3) ^ (r & 3);
    goff[p] = ((p < 4 ? row0 : col0) + r) * K + cb * 16;
  }

  // fragment read offsets (swz = r&3): global block w -> lds block w^swz
  int aro[4][2], bro[2][2];
#pragma unroll
  for (int m = 0; m < 4; ++m) {
    const int r = m * 32 + rl32;
    const int swz = r & 3;
    aro[m][0] = r * 64 + ((hi * 2) ^ swz) * 16;
    aro[m][1] = r * 64 + ((hi * 2 + 1) ^ swz) * 16;
  }
#pragma unroll
  for (int n = 0; n < 2; ++n) {
    const int r = wn * 64 + n * 32 + rl32;
    const int swz = r & 3;
    bro[n][0] = 8192 + r * 64 + ((hi * 2) ^ swz) * 16;
    bro[n][1] = 8192 + r * 64 + ((hi * 2 + 1) ^ swz) * 16;
  }

  // prologue: stage tiles 0 (buf0) and 1 (buf1) — 8 gl_lds each
#pragma unroll
  for (int p = 0; p < 8; ++p)
    gl_lds16((p < 4 ? Aq : Bq) + goff[p], sm[0] + p * 2048 + t * 16);
#pragma unroll
  for (int p = 0; p < 8; ++p)
    gl_lds16((p < 4 ? Aq : Bq) + goff[p] + 64, sm[1] + p * 2048 + t * 16);

  for (int it = 0; it < NT; ++it) {
    const u8* sb = sm[it % 3];
    u8* db = sm[(it + 2) % 3];
    if (it + 2 < NT) {
      const int ko = (it + 2) * 64;
#pragma unroll
      for (int p = 0; p < 8; ++p)
        gl_lds16((p < 4 ? Aq : Bq) + goff[p] + ko, db + p * 2048 + t * 16);
      asm volatile("s_waitcnt vmcnt(16)" ::: "memory");  // tile it landed
    } else if (it + 1 < NT) {
      asm volatile("s_waitcnt vmcnt(8)" ::: "memory");
    } else {
      asm volatile("s_waitcnt vmcnt(0)" ::: "memory");
    }
    __builtin_amdgcn_s_barrier();
    __builtin_amdgcn_sched_barrier(0);

    const i32x8 bv0 = ld32B(sb + bro[0][0], sb + bro[0][1]);
    const i32x8 bv1 = ld32B(sb + bro[1][0], sb + bro[1][1]);
    __builtin_amdgcn_s_setprio(1);
#pragma unroll
    for (int m = 0; m < 4; ++m) {
      const i32x8 av = ld32B(sb + aro[m][0], sb + aro[m][1]);
      acc[m][0] = __builtin_amdgcn_mfma_scale_f32_32x32x64_f8f6f4(
          av, bv0, acc[m][0], 0, 0, 0, 0x7f7f7f7f, 0, 0x7f7f7f7f);
      acc[m][1] = __builtin_amdgcn_mfma_scale_f32_32x32x64_f8f6f4(
          av, bv1, acc[m][1], 0, 0, 0, 0x7f7f7f7f, 0, 0x7f7f7f7f);
    }
    __builtin_amdgcn_s_setprio(0);
    __builtin_amdgcn_sched_barrier(0);
    __builtin_amdgcn_s_barrier();
  }

  // epilogue: resid += (acc * s_token) * wscale_col
  const int cc = rl32;
  const int rb = hi * 4;
  float wvv[2];
#pragma unroll
  for (int n = 0; n < 2; ++n) wvv[n] = wsc[col0 + wn * 64 + n * 32 + cc];
#pragma unroll
  for (int m = 0; m < 4; ++m) {
#pragma unroll
    for (int g2 = 0; g2 < 4; ++g2) {
#pragma unroll
      for (int j = 0; j < 4; ++j) {
        const int row = row0 + m * 32 + g2 * 8 + rb + j;
        const float sv = srow[row];
#pragma unroll
        for (int n = 0; n < 2; ++n) {
          const int col = col0 + wn * 64 + n * 32 + cc;
          const size_t idx = (size_t)row * N + col;
          resid[idx] = resid[idx] + (acc[m][n][g2 * 4 + j] * sv) * wvv[n];
        }
      }
    }
  }
}

extern "C" void kernel_launch(void* const* d_in, const int* in_sizes, int n_in,
                              void* d_out, int out_size, void* d_ws, size_t ws_size,
                              hipStream_t stream) {
  const float* x   = (const float*)d_in[0];
  const float* nw0 = (const float*)d_in[1];
  const float* nw1 = (const float*)d_in[2];
  const float* nw2 = (const float*)d_in[3];
  const float* w0  = (const float*)d_in[4];
  const float* w1  = (const float*)d_in[5];
  const float* ws0 = (const float*)d_in[6];
  const float* ws1 = (const float*)d_in[7];
  float* out = (float*)d_out;

  // workspace: q (T*H fp8) | w0q (H*H fp8) | w1q (H*H fp8) | s (T fp32)  ~= 96.1 MiB
  u8* q = (u8*)d_ws;
  u8* w0q = q + (size_t)TT * HH;
  u8* w1q = w0q + (size_t)HH * HH;
  float* sbuf = (float*)(w1q + (size_t)HH * HH);

  dim3 wg(HH / 64, HH / 64);
  kwquant<<<wg, 256, 0, stream>>>(w0, w0q);
  kwquant<<<wg, 256, 0, stream>>>(w1, w1q);

  knorm<0><<<TT, 256, 0, stream>>>(x, nw0, out, q, sbuf, nullptr);
  kgemm<<<(TT / 128) * (HH / 128), 128, 0, stream>>>(q, w0q, sbuf, ws0, out);
  knorm<1><<<TT, 256, 0, stream>>>(out, nw1, nullptr, q, sbuf, nullptr);
  kgemm<<<(TT / 128) * (HH / 128), 128, 0, stream>>>(q, w1q, sbuf, ws1, out);
  knorm<2><<<TT, 256, 0, stream>>>(out, nw2, nullptr, nullptr, nullptr, out);
}

// Round 17
// 1046.980 us; speedup vs baseline: 1.4397x; 1.0828x over previous
//
#include <hip/hip_runtime.h>
#include <stdint.h>

#define TT 16384
#define HH 4096

typedef uint8_t u8;
typedef uint32_t u32;
typedef __attribute__((ext_vector_type(16))) float f32x16;
typedef __attribute__((ext_vector_type(8))) int i32x8;

// ---- fp8 e4m3 (OCP) pack: 4 floats -> 4 bytes, RNE, saturating ----
__device__ __forceinline__ u32 cvt4_fp8(float a, float b, float c, float d) {
  u32 v = 0;
  v = __builtin_amdgcn_cvt_pk_fp8_f32(a, b, v, false);  // low word
  v = __builtin_amdgcn_cvt_pk_fp8_f32(c, d, v, true);   // high word
  return v;
}

__device__ __forceinline__ void gl_lds16(const void* g, void* l) {
  __builtin_amdgcn_global_load_lds(
      (const __attribute__((address_space(1))) void*)g,
      (__attribute__((address_space(3))) void*)l, 16, 0, 0);
}

__device__ __forceinline__ i32x8 ld32B(const u8* p0, const u8* p1) {
  const uint4 a = *(const uint4*)p0;
  const uint4 b = *(const uint4*)p1;
  i32x8 r;
  r[0] = (int)a.x; r[1] = (int)a.y; r[2] = (int)a.z; r[3] = (int)a.w;
  r[4] = (int)b.x; r[5] = (int)b.y; r[6] = (int)b.z; r[7] = (int)b.w;
  return r;
}

// ---- weight quantize + transpose: w[K][N] fp32 (on fp8 grid) -> wq[N][K] fp8 (plain)
__global__ __launch_bounds__(256) void kwquant(const float* __restrict__ w,
                                               u8* __restrict__ wq) {
  __shared__ __align__(16) u8 tile[64][68];
  const int n0 = blockIdx.x * 64;
  const int k0 = blockIdx.y * 64;
  const int t = threadIdx.x;
  const int tr = t >> 4, tc = t & 15;
#pragma unroll
  for (int p = 0; p < 4; ++p) {
    const int kl = p * 16 + tr;
    const float4 v = *(const float4*)(w + (size_t)(k0 + kl) * HH + n0 + tc * 4);
    const u32 pk = cvt4_fp8(v.x, v.y, v.z, v.w);
    tile[tc * 4 + 0][kl] = (u8)(pk);
    tile[tc * 4 + 1][kl] = (u8)(pk >> 8);
    tile[tc * 4 + 2][kl] = (u8)(pk >> 16);
    tile[tc * 4 + 3][kl] = (u8)(pk >> 24);
  }
  __syncthreads();
  const int jr = t >> 2;
  const int kc = (t & 3) * 16;
  uint4 ov;
  ov.x = *(const u32*)&tile[jr][kc + 0];
  ov.y = *(const u32*)&tile[jr][kc + 4];
  ov.z = *(const u32*)&tile[jr][kc + 8];
  ov.w = *(const u32*)&tile[jr][kc + 12];
  *(uint4*)(wq + (size_t)(n0 + jr) * HH + k0 + kc) = ov;
}

__device__ __forceinline__ float wred_sum(float v) {
#pragma unroll
  for (int o = 32; o; o >>= 1) v += __shfl_down(v, o, 64);
  return v;
}
__device__ __forceinline__ float wred_max(float v) {
#pragma unroll
  for (int o = 32; o; o >>= 1) v = fmaxf(v, __shfl_down(v, o, 64));
  return v;
}

// MODE 0: src=x, write resid=sqrt(x), quantize rmsnorm(x,nw) -> qout,sout
// MODE 1: src=resid, quantize rmsnorm(resid,nw) -> qout,sout
// MODE 2: src=resid, write y=rmsnorm(resid,nw) fp32 -> yout
template <int MODE>
__global__ __launch_bounds__(256) void knorm(const float* __restrict__ src,
                                             const float* __restrict__ nw,
                                             float* __restrict__ resid_out,
                                             u8* __restrict__ qout,
                                             float* __restrict__ sout,
                                             float* __restrict__ yout) {
  __shared__ float red[4];
  __shared__ float redm[4];
  const int row = blockIdx.x;
  const int t = threadIdx.x;
  const int lane = t & 63, wid = t >> 6;
  const float* rp = src + (size_t)row * HH;

  float4 xv[4];
  float ssq = 0.f;
#pragma unroll
  for (int p = 0; p < 4; ++p) {
    xv[p] = *((const float4*)rp + p * 256 + t);
    ssq += xv[p].x * xv[p].x;
    ssq += xv[p].y * xv[p].y;
    ssq += xv[p].z * xv[p].z;
    ssq += xv[p].w * xv[p].w;
  }
  if (MODE == 0) {
    float* rr = resid_out + (size_t)row * HH;
#pragma unroll
    for (int p = 0; p < 4; ++p) {
      float4 r4;
      r4.x = sqrtf(xv[p].x); r4.y = sqrtf(xv[p].y);
      r4.z = sqrtf(xv[p].z); r4.w = sqrtf(xv[p].w);
      *((float4*)rr + p * 256 + t) = r4;
    }
  }
  ssq = wred_sum(ssq);
  if (lane == 0) red[wid] = ssq;
  __syncthreads();
  const float ms = (((red[0] + red[1]) + red[2]) + red[3]) * (1.0f / HH);
  const float inv = 1.0f / sqrtf(ms + 1e-6f);

  float y[16];
  float amax = 0.f;
#pragma unroll
  for (int p = 0; p < 4; ++p) {
    const float4 wv = *((const float4*)nw + p * 256 + t);
    y[p * 4 + 0] = (xv[p].x * inv) * wv.x;
    y[p * 4 + 1] = (xv[p].y * inv) * wv.y;
    y[p * 4 + 2] = (xv[p].z * inv) * wv.z;
    y[p * 4 + 3] = (xv[p].w * inv) * wv.w;
    amax = fmaxf(amax, fabsf(y[p * 4 + 0]));
    amax = fmaxf(amax, fabsf(y[p * 4 + 1]));
    amax = fmaxf(amax, fabsf(y[p * 4 + 2]));
    amax = fmaxf(amax, fabsf(y[p * 4 + 3]));
  }

  if (MODE == 2) {
    float* yp = yout + (size_t)row * HH;
#pragma unroll
    for (int p = 0; p < 4; ++p) {
      float4 o;
      o.x = y[p * 4 + 0]; o.y = y[p * 4 + 1];
      o.z = y[p * 4 + 2]; o.w = y[p * 4 + 3];
      *((float4*)yp + p * 256 + t) = o;
    }
    return;
  }

  amax = wred_max(amax);
  if (lane == 0) redm[wid] = amax;
  __syncthreads();
  const float bmax = fmaxf(fmaxf(redm[0], redm[1]), fmaxf(redm[2], redm[3]));
  const float sval = fmaxf(bmax / 448.0f, 1e-10f);  // ref: max|y|/448, floor 1e-10

  u32* qp = (u32*)(qout + (size_t)row * HH);
#pragma unroll
  for (int p = 0; p < 4; ++p) {
    float q0 = fminf(fmaxf(y[p * 4 + 0] / sval, -448.f), 448.f);
    float q1 = fminf(fmaxf(y[p * 4 + 1] / sval, -448.f), 448.f);
    float q2 = fminf(fmaxf(y[p * 4 + 2] / sval, -448.f), 448.f);
    float q3 = fminf(fmaxf(y[p * 4 + 3] / sval, -448.f), 448.f);
    qp[p * 256 + t] = cvt4_fp8(q0, q1, q2, q3);
  }
  if (t == 0) sout[row] = sval;
}

// ---- fp8 GEMM via MX-scaled MFMA (unit scales => exact fp8 matmul at 2x rate)
// C[t,j] = sum_k Aq[t,k]*Bq[j,k]; resid[t,j] += C*s[t]*wsc[j]
// R17 = R10 (best: 422us) with SINGLE barrier per K-tile.
// R10 needed 2 barriers because staging was issued BEFORE the top barrier
// (fast wave could overwrite buf[(it+2)%3] == buf[(it-1)%3] while a slow wave
// still read it). Moving the stage AFTER the barrier removes the hazard:
// barriers enforce iteration-lockstep, so inside iter it ALL waves have
// finished iter it-1's reads -> staging (it+2)%3 is race-free; stage target
// != it%3 (current reads). One s_barrier per iter (64 vs 128 per GEMM).
// vmcnt ledger: end of iter it outstanding = tiles it+1(4)+it+2(4);
// vmcnt(4) waits it+1 (FIFO), leaves it+2 flying. Prologue: stage t0,t1 ->
// vmcnt(4) (t0 landed) -> barrier. Tail: iter NT-2 ends vmcnt(0).
// Everything else identical to R10: 128x128 tile, 4 waves (2x2), wave 2x2
// frags of 32x32x64; 3-buf ring 48KB (3 blocks/CU); 16B-block swizzle
// cb ^= (r>>1)&3 (R16 proved r&3 is WORSE: 7.5e7 vs 3.36e7 conflicts);
// grouped XCD swizzle (4x4 tile groups = 4MB per-XCD L2 set); setprio(1).
// Frag layout (32x32x64 f8f6f4): lane l -> row/col = l&31, k = (l>>5)*32+byte.
// C/D: col=lane&31, row=(reg&3)+8*(reg>>2)+4*(lane>>5)  [HW-verified m74/m101].
__global__ __launch_bounds__(256) void kgemm(const u8* __restrict__ Aq,
                                             const u8* __restrict__ Bq,
                                             const float* __restrict__ srow,
                                             const float* __restrict__ wsc,
                                             float* __restrict__ resid) {
  constexpr int K = HH, N = HH;
  constexpr int NT = K / 64;
  __shared__ __align__(16) u8 smAf[3 * 128 * 64];  // 24 KiB
  __shared__ __align__(16) u8 smBf[3 * 128 * 64];  // 24 KiB

  // grouped 2-level swizzle (R10): 4x4 (tm,tn) groups per XCD -> 4 MB L2 set
  const int bidraw = blockIdx.x;
  const int xcd = bidraw & 7;
  const int c = bidraw >> 3;            // 0..511
  const int g = c >> 4;                 // 32 groups of 16 blocks
  const int gr = g >> 3, gc = g & 7;    // 4 x 8 grid of groups
  const int gm = (c >> 2) & 3, gn = c & 3;
  const int tm = xcd * 16 + gr * 4 + gm;  // 0..127
  const int tn = gc * 4 + gn;             // 0..31
  const int row0 = tm * 128, col0 = tn * 128;

  const int t = threadIdx.x;
  const int lane = t & 63, wid = t >> 6;
  const int wr = wid >> 1, wc = wid & 1;
  const int rl32 = lane & 31, hi = lane >> 5;

  f32x16 acc[2][2];
#pragma unroll
  for (int m = 0; m < 2; ++m)
#pragma unroll
    for (int n = 0; n < 2; ++n) acc[m][n] = (f32x16)0.f;

  // staging addresses: thread t covers LDS bytes [off, off+16) of each 8KB buffer
  int aoffg[2], boffg[2], ldso[2];
#pragma unroll
  for (int p = 0; p < 2; ++p) {
    const int off = (wid * 2 + p) * 1024 + lane * 16;
    const int r = off >> 6;
    const int cb = ((off >> 4) & 3) ^ ((r >> 1) & 3);  // inverse-swizzled source block
    aoffg[p] = (row0 + r) * K + cb * 16;
    boffg[p] = (col0 + r) * K + cb * 16;
    ldso[p] = off;
  }

  // fragment read offsets within a buffer
  int aro[2][2], bro[2][2];
#pragma unroll
  for (int m = 0; m < 2; ++m) {
    const int r = wr * 64 + m * 32 + rl32;
    const int swz = (r >> 1) & 3;
    aro[m][0] = r * 64 + ((hi * 2) ^ swz) * 16;
    aro[m][1] = r * 64 + ((hi * 2 + 1) ^ swz) * 16;
  }
#pragma unroll
  for (int n = 0; n < 2; ++n) {
    const int r = wc * 64 + n * 32 + rl32;
    const int swz = (r >> 1) & 3;
    bro[n][0] = r * 64 + ((hi * 2) ^ swz) * 16;
    bro[n][1] = r * 64 + ((hi * 2 + 1) ^ swz) * 16;
  }

  // prologue: stage tile 0 (buf 0) then tile 1 (buf 1); wait t0; barrier.
#pragma unroll
  for (int p = 0; p < 2; ++p) {
    gl_lds16(Aq + aoffg[p], smAf + ldso[p]);
    gl_lds16(Bq + boffg[p], smBf + ldso[p]);
  }
#pragma unroll
  for (int p = 0; p < 2; ++p) {
    gl_lds16(Aq + aoffg[p] + 64, smAf + 8192 + ldso[p]);
    gl_lds16(Bq + boffg[p] + 64, smBf + 8192 + ldso[p]);
  }
  asm volatile("s_waitcnt vmcnt(4)" ::: "memory");  // tile 0 landed; tile 1 flying
  __builtin_amdgcn_s_barrier();
  __builtin_amdgcn_sched_barrier(0);

  int bc = 0;  // compute buffer = it % 3
  int bs = 2;  // stage buffer = (it+2) % 3
  for (int it = 0; it < NT; ++it) {
    // inside iter it (post-barrier): all waves done with iter it-1's reads of
    // buf[(it-1)%3] == buf[(it+2)%3] -> safe to stage into it now.
    if (it + 2 < NT) {
      const size_t ko = (size_t)(it + 2) * 64;
      u8* dA = smAf + bs * 8192;
      u8* dB = smBf + bs * 8192;
#pragma unroll
      for (int p = 0; p < 2; ++p) {
        gl_lds16(Aq + aoffg[p] + ko, dA + ldso[p]);
        gl_lds16(Bq + boffg[p] + ko, dB + ldso[p]);
      }
    }

    const u8* sA = smAf + bc * 8192;
    const u8* sB = smBf + bc * 8192;
    i32x8 av[2], bv[2];
#pragma unroll
    for (int m = 0; m < 2; ++m) av[m] = ld32B(sA + aro[m][0], sA + aro[m][1]);
#pragma unroll
    for (int n = 0; n < 2; ++n) bv[n] = ld32B(sB + bro[n][0], sB + bro[n][1]);
    __builtin_amdgcn_s_setprio(1);
#pragma unroll
    for (int m = 0; m < 2; ++m)
#pragma unroll
      for (int n = 0; n < 2; ++n)
        acc[m][n] = __builtin_amdgcn_mfma_scale_f32_32x32x64_f8f6f4(
            av[m], bv[n], acc[m][n], 0 /*A=fp8*/, 0 /*B=fp8*/,
            0, 0x7f7f7f7f, 0, 0x7f7f7f7f);  // e8m0 127 = 2^0 = exact
    __builtin_amdgcn_s_setprio(0);

    // ensure tile it+1 landed before next iter's reads (outstanding:
    // it+1's 4 + it+2's 4 -> wait to 4, FIFO completes it+1 first).
    if (it + 2 < NT) {
      asm volatile("s_waitcnt vmcnt(4)" ::: "memory");
    } else if (it + 1 < NT) {
      asm volatile("s_waitcnt vmcnt(0)" ::: "memory");  // tail: t_{NT-1} landed
    }
    __builtin_amdgcn_sched_barrier(0);
    __builtin_amdgcn_s_barrier();
    __builtin_amdgcn_sched_barrier(0);

    bc = (bc == 2) ? 0 : bc + 1;
    bs = (bs == 2) ? 0 : bs + 1;
  }

  // epilogue: resid += (acc * s_token) * wscale_col
  const int cc = rl32;
  const int rb = hi * 4;
  float wvv[2];
#pragma unroll
  for (int n = 0; n < 2; ++n) wvv[n] = wsc[col0 + wc * 64 + n * 32 + cc];
#pragma unroll
  for (int m = 0; m < 2; ++m) {
#pragma unroll
    for (int g2 = 0; g2 < 4; ++g2) {
#pragma unroll
      for (int j = 0; j < 4; ++j) {
        const int row = row0 + wr * 64 + m * 32 + g2 * 8 + rb + j;
        const float sv = srow[row];
#pragma unroll
        for (int n = 0; n < 2; ++n) {
          const int col = col0 + wc * 64 + n * 32 + cc;
          const size_t idx = (size_t)row * N + col;
          resid[idx] = resid[idx] + (acc[m][n][g2 * 4 + j] * sv) * wvv[n];
        }
      }
    }
  }
}

extern "C" void kernel_launch(void* const* d_in, const int* in_sizes, int n_in,
                              void* d_out, int out_size, void* d_ws, size_t ws_size,
                              hipStream_t stream) {
  const float* x   = (const float*)d_in[0];
  const float* nw0 = (const float*)d_in[1];
  const float* nw1 = (const float*)d_in[2];
  const float* nw2 = (const float*)d_in[3];
  const float* w0  = (const float*)d_in[4];
  const float* w1  = (const float*)d_in[5];
  const float* ws0 = (const float*)d_in[6];
  const float* ws1 = (const float*)d_in[7];
  float* out = (float*)d_out;

  // workspace: q (T*H fp8) | w0q (H*H fp8) | w1q (H*H fp8) | s (T fp32)  ~= 96.1 MiB
  u8* q = (u8*)d_ws;
  u8* w0q = q + (size_t)TT * HH;
  u8* w1q = w0q + (size_t)HH * HH;
  float* sbuf = (float*)(w1q + (size_t)HH * HH);

  dim3 wg(HH / 64, HH / 64);
  kwquant<<<wg, 256, 0, stream>>>(w0, w0q);
  kwquant<<<wg, 256, 0, stream>>>(w1, w1q);

  knorm<0><<<TT, 256, 0, stream>>>(x, nw0, out, q, sbuf, nullptr);
  kgemm<<<(TT / 128) * (HH / 128), 256, 0, stream>>>(q, w0q, sbuf, ws0, out);
  knorm<1><<<TT, 256, 0, stream>>>(out, nw1, nullptr, q, sbuf, nullptr);
  kgemm<<<(TT / 128) * (HH / 128), 256, 0, stream>>>(q, w1q, sbuf, ws1, out);
  knorm<2><<<TT, 256, 0, stream>>>(out, nw2, nullptr, nullptr, nullptr, out);
}